// Round 13
// baseline (284.176 us; speedup 1.0000x reference)
//
#include <hip/hip_runtime.h>
#include <hip/hip_bf16.h>

// Problem constants (B=4, C=256, H=W=64, N=4096, groups=8, heads=4, hd=64)
#define BATCH 4
#define CCH   256
#define NSP   4096          // H*W
#define GRPSZ (32 * 4096)   // elements per group
#define NHEAD 4
#define HD    64

typedef __attribute__((ext_vector_type(8))) short short8;            // 8 bf16 MFMA A/B frag
typedef __attribute__((ext_vector_type(8))) unsigned short ushort8_t;
typedef __attribute__((ext_vector_type(4))) float f32x4;             // MFMA C/D frag

// round-to-nearest-even f32 -> bf16 bits (bit-manip; known-good)
__device__ __forceinline__ unsigned short f2b(float f) {
    unsigned u = __builtin_bit_cast(unsigned, f);
    unsigned r = u + 0x7FFFu + ((u >> 16) & 1u);
    return (unsigned short)(r >> 16);
}
// RNE via HIP intrinsic (compiler emits native cvt) — used on the hot P path
__device__ __forceinline__ unsigned short b16p(float f) {
    __hip_bfloat16 h = __float2bfloat16(f);
    return __builtin_bit_cast(unsigned short, h);
}
// single-instruction 2^x
__device__ __forceinline__ float ex2(float x) {
    float r; asm("v_exp_f32 %0, %1" : "=v"(r) : "v"(x)); return r;
}

// ---------------------------------------------------------------------------
// GroupNorm pass 1: partial sums. grid = 32 groups * 8 chunks, block = 256.
// ---------------------------------------------------------------------------
__global__ __launch_bounds__(256) void gn_partial(const float* __restrict__ x,
                                                  float* __restrict__ sums) {
    int chunk = blockIdx.x & 7;
    int bg    = blockIdx.x >> 3;            // b*8 + g
    const float* base = x + (size_t)bg * GRPSZ + (size_t)chunk * (GRPSZ / 8);
    int t = threadIdx.x;
    float s = 0.f, ss = 0.f;
#pragma unroll
    for (int i = 0; i < 16; ++i) {
        float4 v = *(const float4*)&base[(t + i * 256) * 4];
        s  += v.x + v.y + v.z + v.w;
        ss += v.x * v.x + v.y * v.y + v.z * v.z + v.w * v.w;
    }
    __shared__ float rs[256], rss[256];
    rs[t] = s; rss[t] = ss;
    __syncthreads();
    for (int off = 128; off > 0; off >>= 1) {
        if (t < off) { rs[t] += rs[t + off]; rss[t] += rss[t + off]; }
        __syncthreads();
    }
    if (t == 0) {
        sums[blockIdx.x * 2]     = rs[0];
        sums[blockIdx.x * 2 + 1] = rss[0];
    }
}

// ---------------------------------------------------------------------------
// GroupNorm apply + transpose + bf16 cast, fused.
// x fp32 [b][c][n]  ->  hT bf16 [b][n][c].   grid (64 ntile, 4 ctile, B).
// ---------------------------------------------------------------------------
__global__ __launch_bounds__(256) void gn_pack(const float* __restrict__ x,
                                               const float* __restrict__ sums,
                                               const float* __restrict__ gw,
                                               const float* __restrict__ gb,
                                               unsigned short* __restrict__ hT) {
    __shared__ float LT[64][65];
    __shared__ float wcs[64], bcs[64];
    int b = blockIdx.z, c0 = blockIdx.y * 64, n0 = blockIdx.x * 64;
    int t = threadIdx.x;
    if (t < 64) {
        int c  = c0 + t;
        int bg = b * 8 + (c >> 5);
        float s = 0.f, ss = 0.f;
#pragma unroll
        for (int i = 0; i < 8; ++i) {
            s  += sums[(bg * 8 + i) * 2];
            ss += sums[(bg * 8 + i) * 2 + 1];
        }
        const float invn = 1.f / (float)GRPSZ;
        float mean = s * invn;
        float var  = ss * invn - mean * mean;
        float inv  = rsqrtf(var + 1e-5f);
        float wc = gw[c] * inv;
        wcs[t] = wc;
        bcs[t] = gb[c] - mean * wc;
    }
    __syncthreads();
    int cl4 = (t & 15) * 4, cr = t >> 4;
#pragma unroll
    for (int p = 0; p < 4; ++p) {
        int c = cr + p * 16;
        float4 v = *(const float4*)&x[(size_t)(b * 256 + c0 + c) * 4096 + n0 + cl4];
        float wc = wcs[c], bb = bcs[c];
        LT[c][cl4 + 0] = v.x * wc + bb;
        LT[c][cl4 + 1] = v.y * wc + bb;
        LT[c][cl4 + 2] = v.z * wc + bb;
        LT[c][cl4 + 3] = v.w * wc + bb;
    }
    __syncthreads();
#pragma unroll
    for (int p = 0; p < 2; ++p) {
        int n  = (t >> 3) + p * 32;
        int c8 = (t & 7) * 8;
        ushort8_t w;
#pragma unroll
        for (int i = 0; i < 8; ++i) w[i] = f2b(LT[c8 + i][n]);
        *(ushort8_t*)&hT[((size_t)b * 4096 + n0 + n) * 256 + c0 + c8] = w;
    }
}

// ---------------------------------------------------------------------------
// QKV GEMM, bf16 MFMA.  D[n][o] = sum_c hT[n][c] * W[o][c]  (+bias).
// Q scale folds hd^-0.5 * log2(e) so flash softmax runs in exp2 domain.
// ---------------------------------------------------------------------------
__global__ __launch_bounds__(256) void gemm_qkv(const float* __restrict__ W,
                                                const unsigned short* __restrict__ hT,
                                                const float* __restrict__ bias,
                                                unsigned short* __restrict__ Qbf,
                                                unsigned short* __restrict__ Ktbf,
                                                unsigned short* __restrict__ Vbf) {
    __shared__ unsigned short Wl[64 * 64];   // [o][k ^ ((o&7)<<3)]
    __shared__ unsigned short Hl[64 * 64];   // [n][k ^ ((n&7)<<3)]
    int b = blockIdx.z, o0 = blockIdx.y * 64, n0 = blockIdx.x * 64;
    int t = threadIdx.x, lane = t & 63, wid = t >> 6, g = lane >> 4, cl = lane & 15;
    f32x4 acc[4];
#pragma unroll
    for (int j = 0; j < 4; ++j) acc[j] = (f32x4){0.f, 0.f, 0.f, 0.f};
    int sr = t >> 2;            // staging row 0..63
    int sk = (t & 3) * 16;      // staging k offset
    int swr = (sr & 7) << 3;
    int swa = (cl & 7) << 3;
    for (int k0 = 0; k0 < 256; k0 += 64) {
        __syncthreads();
        {   // W fp32 -> bf16 LDS
            const float* wr = &W[(size_t)(o0 + sr) * 256 + k0 + sk];
            float4 w0 = *(const float4*)&wr[0],  w1 = *(const float4*)&wr[4];
            float4 w2 = *(const float4*)&wr[8],  w3 = *(const float4*)&wr[12];
            ushort8_t u0 = {f2b(w0.x), f2b(w0.y), f2b(w0.z), f2b(w0.w),
                            f2b(w1.x), f2b(w1.y), f2b(w1.z), f2b(w1.w)};
            ushort8_t u1 = {f2b(w2.x), f2b(w2.y), f2b(w2.z), f2b(w2.w),
                            f2b(w3.x), f2b(w3.y), f2b(w3.z), f2b(w3.w)};
            *(ushort8_t*)&Wl[sr * 64 + (sk ^ swr)]       = u0;
            *(ushort8_t*)&Wl[sr * 64 + ((sk + 8) ^ swr)] = u1;
        }
        {   // hT bf16 straight copy
            const ushort8_t* hr = (const ushort8_t*)&hT[((size_t)b * 4096 + n0 + sr) * 256 + k0 + sk];
            *(ushort8_t*)&Hl[sr * 64 + (sk ^ swr)]       = hr[0];
            *(ushort8_t*)&Hl[sr * 64 + ((sk + 8) ^ swr)] = hr[1];
        }
        __syncthreads();
#pragma unroll
        for (int ks = 0; ks < 2; ++ks) {
            short8 a = *(short8*)&Hl[(wid * 16 + cl) * 64 + ((ks * 32 + g * 8) ^ swa)];
#pragma unroll
            for (int j = 0; j < 4; ++j) {
                short8 bb = *(short8*)&Wl[(j * 16 + cl) * 64 + ((ks * 32 + g * 8) ^ swa)];
                acc[j] = __builtin_amdgcn_mfma_f32_16x16x32_bf16(a, bb, acc[j], 0, 0, 0);
            }
        }
    }
    // ---- pack epilogue. D: row(n) = wid*16+g*4+r, col(o) = j*16+cl.
    int sect = blockIdx.y >> 2, head = blockIdx.y & 3;
    size_t tilebase = (((size_t)b * NHEAD + head) * 64 + blockIdx.x) * 4096;
    int nrow = wid * 16 + g * 4;
    if (sect == 0) {
        const float qsc = 0.18033688011112042f;     // hd^-0.5 * log2(e)
#pragma unroll
        for (int j = 0; j < 4; ++j) {
            float bi = bias[o0 + j * 16 + cl];
#pragma unroll
            for (int r = 0; r < 4; ++r)
                Qbf[tilebase + (size_t)(nrow + r) * 64 + j * 16 + cl] =
                    f2b((acc[j][r] + bi) * qsc);
        }
    } else if (sect == 1) {
#pragma unroll
        for (int j = 0; j < 4; ++j) {
            float bi = bias[o0 + j * 16 + cl];
#pragma unroll
            for (int r = 0; r < 4; ++r) {
                int key = nrow + r;
                int sw  = ((key ^ (key >> 3)) & 7) << 3;
                Ktbf[tilebase + (size_t)key * 64 + ((j * 16 + cl) ^ sw)] =
                    f2b(acc[j][r] + bi);
            }
        }
    } else {
        __syncthreads();                    // done reading Wl
        unsigned short* VL = Wl;            // reuse 8KB as [d][key^sw(d)]
#pragma unroll
        for (int j = 0; j < 4; ++j) {
            float bi = bias[o0 + j * 16 + cl];
            int d = j * 16 + cl;
#pragma unroll
            for (int r = 0; r < 4; ++r) {
                int key = nrow + r;
                VL[d * 64 + (key ^ ((d & 7) << 3))] = f2b(acc[j][r] + bi);
            }
        }
        __syncthreads();
        ushort8_t* dst = (ushort8_t*)&Vbf[tilebase];
        const ushort8_t* srcl = (const ushort8_t*)VL;
        dst[t]       = srcl[t];
        dst[t + 256] = srcl[t + 256];
    }
}

// ---------------------------------------------------------------------------
// Proj GEMM, bf16 MFMA.  Out[o][n] = sum_c W[o][c]*aT[n][c] + bias[o] + x.
// ---------------------------------------------------------------------------
__global__ __launch_bounds__(256) void gemm_proj(const float* __restrict__ W,
                                                 const unsigned short* __restrict__ aT,
                                                 const float* __restrict__ bias,
                                                 const float* __restrict__ x,
                                                 float* __restrict__ Out) {
    __shared__ unsigned short Wl[64 * 64];   // [o][k ^ sw(o)]
    __shared__ unsigned short Al[64 * 64];   // [n][k ^ sw(n)]
    int b = blockIdx.z, o0 = blockIdx.y * 64, n0 = blockIdx.x * 64;
    int t = threadIdx.x, lane = t & 63, wid = t >> 6, g = lane >> 4, cl = lane & 15;
    f32x4 acc[4];
#pragma unroll
    for (int j = 0; j < 4; ++j) acc[j] = (f32x4){0.f, 0.f, 0.f, 0.f};
    int sr = t >> 2, sk = (t & 3) * 16;
    int swr = (sr & 7) << 3;
    int swa = (cl & 7) << 3;
    for (int k0 = 0; k0 < 256; k0 += 64) {
        __syncthreads();
        {
            const float* wr = &W[(size_t)(o0 + sr) * 256 + k0 + sk];
            float4 w0 = *(const float4*)&wr[0],  w1 = *(const float4*)&wr[4];
            float4 w2 = *(const float4*)&wr[8],  w3 = *(const float4*)&wr[12];
            ushort8_t u0 = {f2b(w0.x), f2b(w0.y), f2b(w0.z), f2b(w0.w),
                            f2b(w1.x), f2b(w1.y), f2b(w1.z), f2b(w1.w)};
            ushort8_t u1 = {f2b(w2.x), f2b(w2.y), f2b(w2.z), f2b(w2.w),
                            f2b(w3.x), f2b(w3.y), f2b(w3.z), f2b(w3.w)};
            *(ushort8_t*)&Wl[sr * 64 + (sk ^ swr)]       = u0;
            *(ushort8_t*)&Wl[sr * 64 + ((sk + 8) ^ swr)] = u1;
        }
        {
            const ushort8_t* ar = (const ushort8_t*)&aT[((size_t)b * 4096 + n0 + sr) * 256 + k0 + sk];
            *(ushort8_t*)&Al[sr * 64 + (sk ^ swr)]       = ar[0];
            *(ushort8_t*)&Al[sr * 64 + ((sk + 8) ^ swr)] = ar[1];
        }
        __syncthreads();
#pragma unroll
        for (int ks = 0; ks < 2; ++ks) {
            short8 a = *(short8*)&Wl[(wid * 16 + cl) * 64 + ((ks * 32 + g * 8) ^ swa)];
#pragma unroll
            for (int j = 0; j < 4; ++j) {
                short8 bb = *(short8*)&Al[(j * 16 + cl) * 64 + ((ks * 32 + g * 8) ^ swa)];
                acc[j] = __builtin_amdgcn_mfma_f32_16x16x32_bf16(a, bb, acc[j], 0, 0, 0);
            }
        }
    }
    float bi[4];
#pragma unroll
    for (int r = 0; r < 4; ++r) bi[r] = bias[o0 + wid * 16 + g * 4 + r];
#pragma unroll
    for (int r = 0; r < 4; ++r) {
        int o = o0 + wid * 16 + g * 4 + r;
        size_t rowbase = ((size_t)b * 256 + o) * 4096 + n0;
#pragma unroll
        for (int j = 0; j < 4; ++j) {
            size_t idx = rowbase + j * 16 + cl;
            Out[idx] = acc[j][r] + bi[r] + x[idx];
        }
    }
}

// ---------------------------------------------------------------------------
// MFMA flash attention v4: QBLK=128 (2 q-fragments per wave) — halves per-CU
// staging/barrier/K-V-frag DS work; each kf/vf LDS read now feeds 2 MFMAs.
// grid = (N/128, heads, B) = (32,4,4), block = 256 (4 waves x 32 queries).
// LDS 48KB: K0 K1 V0 V1 (8KB each) + P (16KB). 2 blocks/CU (grid-limited).
// exp2-domain softmax + defer-max + single-barrier double-buffer from v3.
// ---------------------------------------------------------------------------
__global__ __launch_bounds__(256, 2) void flash_mfma(const unsigned short* __restrict__ Qbf,
                                                     const unsigned short* __restrict__ Ktbf,
                                                     const unsigned short* __restrict__ Vbf,
                                                     unsigned short* __restrict__ aoutbf) {
    __shared__ unsigned short Kbuf[2][4096];   // [64 key][64 d] swizzled, x2
    __shared__ unsigned short Vbuf[2][4096];   // [64 d][64 key] swizzled, x2
    __shared__ unsigned short Pbuf[8192];      // 4 waves x [32 q][64 k]

    const int t    = threadIdx.x;
    const int lane = t & 63;
    const int wid  = t >> 6;
    const int g    = lane >> 4;
    const int cl   = lane & 15;

    const int head = blockIdx.y, b = blockIdx.z;
    const int bh   = b * NHEAD + head;

    // Q: 2 fragments per wave, q = bx*128 + f*64 + wid*16 + cl
    short8 qf[2][2];
#pragma unroll
    for (int f = 0; f < 2; ++f) {
        const unsigned short* Qt = Qbf + (((size_t)bh * 64 + blockIdx.x * 2 + f) * 4096);
        qf[f][0] = *(const short8*)&Qt[(wid * 16 + cl) * 64 + g * 8];
        qf[f][1] = *(const short8*)&Qt[(wid * 16 + cl) * 64 + 32 + g * 8];
    }

    const ushort8_t* kg = (const ushort8_t*)(Ktbf + (size_t)bh * 64 * 4096);
    const ushort8_t* vg = (const ushort8_t*)(Vbf  + (size_t)bh * 64 * 4096);

    f32x4 o_acc[2][4];
#pragma unroll
    for (int f = 0; f < 2; ++f)
#pragma unroll
        for (int ds = 0; ds < 4; ++ds) o_acc[f][ds] = (f32x4){0.f, 0.f, 0.f, 0.f};
    float m[2][4], l[2][4];
#pragma unroll
    for (int f = 0; f < 2; ++f)
#pragma unroll
        for (int r = 0; r < 4; ++r) { m[f][r] = -1e30f; l[f][r] = 0.f; }

    // prologue: stage tile 0
    ushort8_t kr0 = kg[t], kr1 = kg[t + 256];
    ushort8_t vr0 = vg[t], vr1 = vg[t + 256];
    ((ushort8_t*)&Kbuf[0][0])[t] = kr0;  ((ushort8_t*)&Kbuf[0][0])[t + 256] = kr1;
    ((ushort8_t*)&Vbuf[0][0])[t] = vr0;  ((ushort8_t*)&Vbuf[0][0])[t + 256] = vr1;
    __syncthreads();

    for (int tile = 0; tile < 64; ++tile) {
        const int cur = tile & 1;
        const unsigned short* KT = &Kbuf[cur][0];
        const unsigned short* VS = &Vbuf[cur][0];
        // issue next tile's global loads (latency hides under compute)
        if (tile < 63) {
            const ushort8_t* kn = kg + (size_t)(tile + 1) * 512;
            const ushort8_t* vn = vg + (size_t)(tile + 1) * 512;
            kr0 = kn[t]; kr1 = kn[t + 256];
            vr0 = vn[t]; vr1 = vn[t + 256];
        }

        // ---- S = Q^T K : each kf read feeds both q-fragments
        f32x4 accs[2][4];
#pragma unroll
        for (int f = 0; f < 2; ++f)
#pragma unroll
            for (int s = 0; s < 4; ++s) accs[f][s] = (f32x4){0.f, 0.f, 0.f, 0.f};
#pragma unroll
        for (int s = 0; s < 4; ++s) {
            int row = s * 16 + cl;
            int sw  = ((row ^ (row >> 3)) & 7) << 3;
#pragma unroll
            for (int h = 0; h < 2; ++h) {
                short8 kf = *(const short8*)&KT[row * 64 + ((h * 32 + g * 8) ^ sw)];
                accs[0][s] = __builtin_amdgcn_mfma_f32_16x16x32_bf16(qf[0][h], kf, accs[0][s], 0, 0, 0);
                accs[1][s] = __builtin_amdgcn_mfma_f32_16x16x32_bf16(qf[1][h], kf, accs[1][s], 0, 0, 0);
            }
        }

        // ---- online softmax, exp2 domain, defer-max (THR=8 -> P <= 256)
        float nm[2][4];
        int need = 0;
#pragma unroll
        for (int f = 0; f < 2; ++f)
#pragma unroll
            for (int r = 0; r < 4; ++r) {
                float rm = fmaxf(fmaxf(accs[f][0][r], accs[f][1][r]),
                                 fmaxf(accs[f][2][r], accs[f][3][r]));
#pragma unroll
                for (int mask = 1; mask < 16; mask <<= 1)
                    rm = fmaxf(rm, __shfl_xor(rm, mask));
                nm[f][r] = fmaxf(m[f][r], rm);
                need |= (rm > m[f][r] + 8.f) ? 1 : 0;
            }
        if (__any(need)) {
#pragma unroll
            for (int f = 0; f < 2; ++f)
#pragma unroll
                for (int r = 0; r < 4; ++r) {
                    float corr = ex2(m[f][r] - nm[f][r]);
                    l[f][r] *= corr;
                    o_acc[f][0][r] *= corr; o_acc[f][1][r] *= corr;
                    o_acc[f][2][r] *= corr; o_acc[f][3][r] *= corr;
                    m[f][r] = nm[f][r];
                }
        }
        unsigned short pb16[2][4][4];
#pragma unroll
        for (int f = 0; f < 2; ++f)
#pragma unroll
            for (int r = 0; r < 4; ++r) {
                float ps = 0.f;
#pragma unroll
                for (int s = 0; s < 4; ++s) {
                    float p = ex2(accs[f][s][r] - m[f][r]);
                    ps += p;
                    pb16[f][r][s] = b16p(p);
                }
                l[f][r] += ps;
            }

        // ---- P -> per-wave LDS (rows 0..31 = f*16 + g*4 + r), then PV MFMAs
        unsigned short* Pw = &Pbuf[wid * 2048];
#pragma unroll
        for (int f = 0; f < 2; ++f)
#pragma unroll
            for (int r = 0; r < 4; ++r) {
                int row = f * 16 + g * 4 + r;
#pragma unroll
                for (int s = 0; s < 4; ++s) {
                    int col = s * 16 + cl;
                    Pw[row * 64 + (col ^ ((row & 7) << 3))] = pb16[f][r][s];
                }
            }
#pragma unroll
        for (int h2 = 0; h2 < 2; ++h2) {
            int off = (h2 * 32 + g * 8) ^ ((cl & 7) << 3);
            short8 pf0 = *(const short8*)&Pw[cl * 64 + off];
            short8 pf1 = *(const short8*)&Pw[(16 + cl) * 64 + off];
#pragma unroll
            for (int ds = 0; ds < 4; ++ds) {
                int vrow = ds * 16 + cl;
                short8 vf = *(const short8*)&VS[vrow * 64 + off];
                o_acc[0][ds] = __builtin_amdgcn_mfma_f32_16x16x32_bf16(pf0, vf, o_acc[0][ds], 0, 0, 0);
                o_acc[1][ds] = __builtin_amdgcn_mfma_f32_16x16x32_bf16(pf1, vf, o_acc[1][ds], 0, 0, 0);
            }
        }

        // commit next tile into the other buffer, single barrier per tile
        if (tile < 63) {
            ushort8_t* KN = (ushort8_t*)&Kbuf[cur ^ 1][0];
            ushort8_t* VN = (ushort8_t*)&Vbuf[cur ^ 1][0];
            KN[t] = kr0;  KN[t + 256] = kr1;
            VN[t] = vr0;  VN[t + 256] = vr1;
        }
        __syncthreads();
    }

    // ---- finalize: reduce l, write aout[q][c] bf16
#pragma unroll
    for (int f = 0; f < 2; ++f) {
        float inv[4];
#pragma unroll
        for (int r = 0; r < 4; ++r) {
            float s = l[f][r];
#pragma unroll
            for (int mask = 1; mask < 16; mask <<= 1) s += __shfl_xor(s, mask);
            inv[r] = 1.f / s;
        }
        unsigned short* Ab = aoutbf +
            ((size_t)b * 4096 + blockIdx.x * 128 + f * 64 + wid * 16) * 256 + head * 64;
#pragma unroll
        for (int ds = 0; ds < 4; ++ds)
#pragma unroll
            for (int r = 0; r < 4; ++r)
                Ab[(size_t)(g * 4 + r) * 256 + ds * 16 + cl] = f2b(o_acc[f][ds][r] * inv[r]);
    }
}

// ---------------------------------------------------------------------------
extern "C" void kernel_launch(void* const* d_in, const int* in_sizes, int n_in,
                              void* d_out, int out_size, void* d_ws, size_t ws_size,
                              hipStream_t stream) {
    const float* x    = (const float*)d_in[0];
    const float* nw   = (const float*)d_in[1];
    const float* nb   = (const float*)d_in[2];
    const float* qkvw = (const float*)d_in[3];
    const float* qkvb = (const float*)d_in[4];
    const float* pw   = (const float*)d_in[5];
    const float* pb   = (const float*)d_in[6];
    float* out = (float*)d_out;

    // ws layout (~40.1 MB):
    //   [0, 2KB)        gn partial sums
    //   [64KB, +8MB)    hT   bf16 [b][n][c]
    //   [+8MB each]     Qbf / Ktbf / Vbf  (packed per 64-tile, flash layouts)
    //   [+8MB]          aoutbf bf16 [b][q][c]
    char* ws = (char*)d_ws;
    float* sums = (float*)ws;
    unsigned short* hT     = (unsigned short*)(ws + (1 << 16));
    unsigned short* Qbf    = hT     + (size_t)BATCH * NSP * CCH;
    unsigned short* Ktbf   = Qbf    + (size_t)BATCH * NHEAD * NSP * HD;
    unsigned short* Vbf    = Ktbf   + (size_t)BATCH * NHEAD * NSP * HD;
    unsigned short* aoutbf = Vbf    + (size_t)BATCH * NHEAD * NSP * HD;

    gn_partial<<<dim3(256), dim3(256), 0, stream>>>(x, sums);
    gn_pack<<<dim3(64, 4, BATCH), dim3(256), 0, stream>>>(x, sums, nw, nb, hT);
    gemm_qkv<<<dim3(64, 12, BATCH), dim3(256), 0, stream>>>(qkvw, hT, qkvb, Qbf, Ktbf, Vbf);
    flash_mfma<<<dim3(32, NHEAD, BATCH), dim3(256), 0, stream>>>(Qbf, Ktbf, Vbf, aoutbf);
    gemm_proj<<<dim3(64, 4, BATCH), dim3(256), 0, stream>>>(pw, aoutbf, pb, x, out);
}